// Round 1
// baseline (168.134 us; speedup 1.0000x reference)
//
#include <hip/hip_runtime.h>
#include <math.h>

#define HH 512
#define WW 512
#define NPIX (HH*WW)
#define MPTS 100
#define BSZ 4

static constexpr float MAXD = 724.0773439350246f;  // sqrt(512^2 + 512^2)
static constexpr float EPSF = 1e-6f;

__device__ __forceinline__ float wred(float v) {
#pragma unroll
  for (int off = 32; off > 0; off >>= 1) v += __shfl_down(v, off);
  return v;
}

// ws layout (floats): [0..3] t1 numerator per batch, [4..7] n_est per batch,
//                     [8..407] S[b][m] = sum_n (wd+eps)^-9
__global__ __launch_bounds__(256) void k_term1(
    const float* __restrict__ pm, const float* __restrict__ gt,
    const float* __restrict__ osz, float* __restrict__ acc) {
  const int PT = 2;  // float4 groups per thread
  int b = blockIdx.y;
  __shared__ float2 gts[MPTS];
  float nyn = osz[2*b+0] * (1.0f/HH);
  float nxn = osz[2*b+1] * (1.0f/WW);
  for (int i = threadIdx.x; i < MPTS; i += 256)
    gts[i] = make_float2(gt[(b*MPTS+i)*2+0]*nyn, gt[(b*MPTS+i)*2+1]*nxn);
  __syncthreads();
  const float4* pm4 = (const float4*)(pm + (size_t)b*NPIX);
  int base = blockIdx.x * (256*PT);
  float t1p = 0.0f, np = 0.0f;
#pragma unroll
  for (int t = 0; t < PT; ++t) {
    int q = base + t*256 + (int)threadIdx.x;
    float4 p4 = pm4[q];
    int n0 = q << 2;
    float py  = (float)(n0 >> 9) * nyn;
    float px0 = (float)(n0 & 511) * nxn;
    float m0=1e30f, m1=1e30f, m2=1e30f, m3=1e30f;
#pragma unroll 4
    for (int m = 0; m < MPTS; ++m) {
      float2 g = gts[m];
      float dy  = py - g.x;
      float dy2 = dy*dy;
      float d0 = px0 - g.y;
      float d1 = d0 + nxn;
      float d2 = d1 + nxn;
      float d3 = d2 + nxn;
      m0 = fminf(m0, fmaf(d0, d0, dy2));
      m1 = fminf(m1, fmaf(d1, d1, dy2));
      m2 = fminf(m2, fmaf(d2, d2, dy2));
      m3 = fminf(m3, fmaf(d3, d3, dy2));
    }
    t1p += p4.x*__builtin_amdgcn_sqrtf(m0);
    t1p += p4.y*__builtin_amdgcn_sqrtf(m1);
    t1p += p4.z*__builtin_amdgcn_sqrtf(m2);
    t1p += p4.w*__builtin_amdgcn_sqrtf(m3);
    np  += (p4.x + p4.y) + (p4.z + p4.w);
  }
  t1p = wred(t1p);
  np  = wred(np);
  if ((threadIdx.x & 63) == 0) {
    atomicAdd(&acc[b],     t1p);
    atomicAdd(&acc[4 + b], np);
  }
}

__global__ __launch_bounds__(256) void k_term2(
    const float* __restrict__ pm, const float* __restrict__ gt,
    const float* __restrict__ osz, float* __restrict__ S) {
  const int TM = 10;   // GT points per block
  const int PB = 8;    // float4 groups per thread
  int b  = blockIdx.z;
  int mg = blockIdx.y;
  float nyn = osz[2*b+0] * (1.0f/HH);
  float nxn = osz[2*b+1] * (1.0f/WW);
  float gy[TM], gx[TM];
#pragma unroll
  for (int j = 0; j < TM; ++j) {
    int m = mg*TM + j;
    gy[j] = gt[(b*MPTS+m)*2+0]*nyn;
    gx[j] = gt[(b*MPTS+m)*2+1]*nxn;
  }
  float acc[TM];
#pragma unroll
  for (int j = 0; j < TM; ++j) acc[j] = 0.0f;
  const float4* pm4 = (const float4*)(pm + (size_t)b*NPIX);
  int base = blockIdx.x * (256*PB);
  for (int t = 0; t < PB; ++t) {
    int q = base + t*256 + (int)threadIdx.x;
    float4 p4 = pm4[q];
    int n0 = q << 2;
    float py  = (float)(n0 >> 9) * nyn;
    float px0 = (float)(n0 & 511) * nxn;
    // c = (1-p)*MAXD + EPS
    float c0 = fmaf(-p4.x, MAXD, MAXD + EPSF);
    float c1 = fmaf(-p4.y, MAXD, MAXD + EPSF);
    float c2 = fmaf(-p4.z, MAXD, MAXD + EPSF);
    float c3 = fmaf(-p4.w, MAXD, MAXD + EPSF);
#pragma unroll
    for (int j = 0; j < TM; ++j) {
      float dy  = py - gy[j];
      float dy2 = dy*dy;
      float dx0 = px0 - gx[j];
      float dx1 = dx0 + nxn;
      float dx2 = dx1 + nxn;
      float dx3 = dx2 + nxn;
      float w0 = fmaf(p4.x, __builtin_amdgcn_sqrtf(fmaf(dx0,dx0,dy2)), c0);
      float w1 = fmaf(p4.y, __builtin_amdgcn_sqrtf(fmaf(dx1,dx1,dy2)), c1);
      float w2 = fmaf(p4.z, __builtin_amdgcn_sqrtf(fmaf(dx2,dx2,dy2)), c2);
      float w3 = fmaf(p4.w, __builtin_amdgcn_sqrtf(fmaf(dx3,dx3,dy2)), c3);
      float i0 = __builtin_amdgcn_rcpf(w0);
      float i1 = __builtin_amdgcn_rcpf(w1);
      float i2 = __builtin_amdgcn_rcpf(w2);
      float i3 = __builtin_amdgcn_rcpf(w3);
      float a0 = i0*i0; a0 *= a0; a0 *= a0;   // i0^8
      float a1 = i1*i1; a1 *= a1; a1 *= a1;
      float a2 = i2*i2; a2 *= a2; a2 *= a2;
      float a3 = i3*i3; a3 *= a3; a3 *= a3;
      float s = fmaf(a0, i0, acc[j]);
      s = fmaf(a1, i1, s);
      s = fmaf(a2, i2, s);
      acc[j] = fmaf(a3, i3, s);
    }
  }
#pragma unroll
  for (int j = 0; j < TM; ++j) {
    float v = wred(acc[j]);
    if ((threadIdx.x & 63) == 0) atomicAdd(&S[b*MPTS + mg*TM + j], v);
  }
}

__global__ __launch_bounds__(512) void k_final(
    const float* __restrict__ ws, float* __restrict__ out) {
  __shared__ float red[512];
  int i = threadIdx.x;
  float v = 0.0f;
  if (i < BSZ*MPTS) {
    float mean = ws[8 + i] * (1.0f/(float)NPIX);
    v = powf(mean, -1.0f/9.0f);   // mean ** (1/P_EXP), P_EXP = -9
  }
  red[i] = v;
  __syncthreads();
  for (int s = 256; s > 0; s >>= 1) {
    if (i < s) red[i] += red[i+s];
    __syncthreads();
  }
  if (i == 0) {
    float t2 = red[0] * (1.0f/(float)(BSZ*MPTS));
    float t1 = 0.0f;
    for (int b = 0; b < BSZ; ++b) t1 += ws[b] / (ws[4+b] + EPSF);
    out[0] = t1 * (1.0f/(float)BSZ) + t2;
  }
}

extern "C" void kernel_launch(void* const* d_in, const int* in_sizes, int n_in,
                              void* d_out, int out_size, void* d_ws, size_t ws_size,
                              hipStream_t stream) {
  const float* pm  = (const float*)d_in[0];
  const float* gt  = (const float*)d_in[1];
  const float* osz = (const float*)d_in[2];
  float* out = (float*)d_out;
  float* ws  = (float*)d_ws;

  hipMemsetAsync(d_ws, 0, 408*sizeof(float), stream);

  // term1: 4-pixel tiles, PT=2 float4/thread -> 512 px/block, 128 blocks/batch
  k_term1<<<dim3(NPIX/4/(256*2), BSZ), 256, 0, stream>>>(pm, gt, osz, ws);

  // term2: 32 chunks x 10 m-groups x 4 batches = 1280 blocks
  k_term2<<<dim3(NPIX/4/(256*8), MPTS/10, BSZ), 256, 0, stream>>>(pm, gt, osz, ws + 8);

  k_final<<<1, 512, 0, stream>>>(ws, out);
}

// Round 2
// 108.116 us; speedup vs baseline: 1.5551x; 1.5551x over previous
//
#include <hip/hip_runtime.h>
#include <math.h>

#define HH 512
#define WW 512
#define NPIX (HH*WW)
#define MPTS 100
#define BSZ 4

static constexpr float MAXD = 724.0773439350246f;  // sqrt(512^2 + 512^2)
static constexpr float EPSF = 1e-6f;

__device__ __forceinline__ float wred(float v) {
#pragma unroll
  for (int off = 32; off > 0; off >>= 1) v += __shfl_down(v, off);
  return v;
}

// ws layout (floats): [0..3] t1 numerator per batch, [4..7] n_est per batch,
//                     [8..407] S[b][m] = sum_n (wd+eps)^-9
__global__ __launch_bounds__(256) void k_term1(
    const float* __restrict__ pm, const float* __restrict__ gt,
    const float* __restrict__ osz, float* __restrict__ acc) {
  int b = blockIdx.y;
  __shared__ float2 gts[MPTS];
  __shared__ float r1[4], r2[4];
  float nyn = osz[2*b+0] * (1.0f/HH);
  float nxn = osz[2*b+1] * (1.0f/WW);
  for (int i = threadIdx.x; i < MPTS; i += 256)
    gts[i] = make_float2(gt[(b*MPTS+i)*2+0]*nyn, gt[(b*MPTS+i)*2+1]*nxn);
  __syncthreads();
  const float2* pm2 = (const float2*)(pm + (size_t)b*NPIX);
  int q = blockIdx.x*256 + (int)threadIdx.x;   // float2 index
  float2 p2 = pm2[q];
  int n0 = q << 1;
  float py  = (float)(n0 >> 9) * nyn;
  float px0 = (float)(n0 & 511) * nxn;
  float px1 = px0 + nxn;
  float mA = 1e30f, mB = 1e30f;
#pragma unroll 5
  for (int m = 0; m < MPTS; m += 2) {
    float2 ga = gts[m];
    float2 gb = gts[m+1];
    float dya = py - ga.x; float ya2 = dya*dya;
    float dyb = py - gb.x; float yb2 = dyb*dyb;
    float a0 = px0 - ga.y, b0 = px0 - gb.y;
    float a1 = px1 - ga.y, b1 = px1 - gb.y;
    // fminf(chain, fminf(x,y)) -> v_min3_f32: halves the dep chain
    mA = fminf(mA, fminf(fmaf(a0,a0,ya2), fmaf(b0,b0,yb2)));
    mB = fminf(mB, fminf(fmaf(a1,a1,ya2), fmaf(b1,b1,yb2)));
  }
  float t1p = p2.x*__builtin_amdgcn_sqrtf(mA) + p2.y*__builtin_amdgcn_sqrtf(mB);
  float np  = p2.x + p2.y;
  t1p = wred(t1p);
  np  = wred(np);
  int w = threadIdx.x >> 6;
  if ((threadIdx.x & 63) == 0) { r1[w] = t1p; r2[w] = np; }
  __syncthreads();
  if (threadIdx.x == 0) {
    atomicAdd(&acc[b],     (r1[0]+r1[1])+(r1[2]+r1[3]));
    atomicAdd(&acc[4 + b], (r2[0]+r2[1])+(r2[2]+r2[3]));
  }
}

__global__ __launch_bounds__(256) void k_term2(
    const float* __restrict__ pm, const float* __restrict__ gt,
    const float* __restrict__ osz, float* __restrict__ S) {
  const int TM = 10;   // GT points per block
  const int PB = 2;    // float4 groups per thread
  int b  = blockIdx.z;
  int mg = blockIdx.y;
  __shared__ float sacc[TM];
  if (threadIdx.x < TM) sacc[threadIdx.x] = 0.0f;
  float nyn = osz[2*b+0] * (1.0f/HH);
  float nxn = osz[2*b+1] * (1.0f/WW);
  float gy[TM], gx[TM];
#pragma unroll
  for (int j = 0; j < TM; ++j) {
    int m = mg*TM + j;
    gy[j] = gt[(b*MPTS+m)*2+0]*nyn;
    gx[j] = gt[(b*MPTS+m)*2+1]*nxn;
  }
  float acc[TM];
#pragma unroll
  for (int j = 0; j < TM; ++j) acc[j] = 0.0f;
  const float4* pm4 = (const float4*)(pm + (size_t)b*NPIX);
  int base = blockIdx.x * (256*PB);
#pragma unroll
  for (int t = 0; t < PB; ++t) {
    int q = base + t*256 + (int)threadIdx.x;
    float4 p4 = pm4[q];
    int n0 = q << 2;
    float py  = (float)(n0 >> 9) * nyn;
    float px0 = (float)(n0 & 511) * nxn;
    // c = (1-p)*MAXD + EPS
    float c0 = fmaf(-p4.x, MAXD, MAXD + EPSF);
    float c1 = fmaf(-p4.y, MAXD, MAXD + EPSF);
    float c2 = fmaf(-p4.z, MAXD, MAXD + EPSF);
    float c3 = fmaf(-p4.w, MAXD, MAXD + EPSF);
#pragma unroll
    for (int j = 0; j < TM; ++j) {
      float dy  = py - gy[j];
      float dy2 = dy*dy;
      float dx0 = px0 - gx[j];
      float dx1 = dx0 + nxn;
      float dx2 = dx1 + nxn;
      float dx3 = dx2 + nxn;
      float w0 = fmaf(p4.x, __builtin_amdgcn_sqrtf(fmaf(dx0,dx0,dy2)), c0);
      float w1 = fmaf(p4.y, __builtin_amdgcn_sqrtf(fmaf(dx1,dx1,dy2)), c1);
      float w2 = fmaf(p4.z, __builtin_amdgcn_sqrtf(fmaf(dx2,dx2,dy2)), c2);
      float w3 = fmaf(p4.w, __builtin_amdgcn_sqrtf(fmaf(dx3,dx3,dy2)), c3);
      float i0 = __builtin_amdgcn_rcpf(w0);
      float i1 = __builtin_amdgcn_rcpf(w1);
      float i2 = __builtin_amdgcn_rcpf(w2);
      float i3 = __builtin_amdgcn_rcpf(w3);
      float a0 = i0*i0; a0 *= a0; a0 *= a0;   // i0^8
      float a1 = i1*i1; a1 *= a1; a1 *= a1;
      float a2 = i2*i2; a2 *= a2; a2 *= a2;
      float a3 = i3*i3; a3 *= a3; a3 *= a3;
      float s = fmaf(a0, i0, acc[j]);
      s = fmaf(a1, i1, s);
      s = fmaf(a2, i2, s);
      acc[j] = fmaf(a3, i3, s);
    }
  }
  __syncthreads();   // sacc init visible
#pragma unroll
  for (int j = 0; j < TM; ++j) {
    float v = wred(acc[j]);
    if ((threadIdx.x & 63) == 0) atomicAdd(&sacc[j], v);
  }
  __syncthreads();
  if (threadIdx.x < TM)
    atomicAdd(&S[b*MPTS + mg*TM + (int)threadIdx.x], sacc[threadIdx.x]);
}

__global__ __launch_bounds__(512) void k_final(
    const float* __restrict__ ws, float* __restrict__ out) {
  __shared__ float red[512];
  int i = threadIdx.x;
  float v = 0.0f;
  if (i < BSZ*MPTS) {
    float mean = ws[8 + i] * (1.0f/(float)NPIX);
    v = powf(mean, -1.0f/9.0f);   // mean ** (1/P_EXP), P_EXP = -9
  }
  red[i] = v;
  __syncthreads();
  for (int s = 256; s > 0; s >>= 1) {
    if (i < s) red[i] += red[i+s];
    __syncthreads();
  }
  if (i == 0) {
    float t2 = red[0] * (1.0f/(float)(BSZ*MPTS));
    float t1 = 0.0f;
    for (int b = 0; b < BSZ; ++b) t1 += ws[b] / (ws[4+b] + EPSF);
    out[0] = t1 * (1.0f/(float)BSZ) + t2;
  }
}

extern "C" void kernel_launch(void* const* d_in, const int* in_sizes, int n_in,
                              void* d_out, int out_size, void* d_ws, size_t ws_size,
                              hipStream_t stream) {
  const float* pm  = (const float*)d_in[0];
  const float* gt  = (const float*)d_in[1];
  const float* osz = (const float*)d_in[2];
  float* out = (float*)d_out;
  float* ws  = (float*)d_ws;

  hipMemsetAsync(d_ws, 0, 408*sizeof(float), stream);

  // term1: float2/thread -> 512 blocks/batch, 2048 total (8/CU, full occupancy)
  k_term1<<<dim3(NPIX/2/256, BSZ), 256, 0, stream>>>(pm, gt, osz, ws);

  // term2: 128 chunks x 10 m-groups x 4 batches = 5120 blocks
  k_term2<<<dim3(NPIX/4/(256*2), MPTS/10, BSZ), 256, 0, stream>>>(pm, gt, osz, ws + 8);

  k_final<<<1, 512, 0, stream>>>(ws, out);
}

// Round 3
// 54.764 us; speedup vs baseline: 3.0701x; 1.9742x over previous
//
#include <hip/hip_runtime.h>
#include <math.h>

#define HH 512
#define WW 512
#define NPIX (HH*WW)
#define MPTS 100
#define BSZ 4
#define T1B 256   // term1 blocks per batch
#define NCH 64    // term2 chunks per (b, m-group)
#define TM 10     // GT points per term2 block

static constexpr float MAXD = 724.0773439350246f;  // sqrt(512^2 + 512^2)
static constexpr float EPSF = 1e-6f;

// ws float layout (all plain stores, no atomics, no memset needed):
// [0, 1024)        T1P[b][T1B]   term1 weighted-min partial per block
// [1024, 2048)     NP [b][T1B]   n_est partial per block
// [2048, 27648)    S2 [(b*100+m)][NCH]  term2 (wd+eps)^-9 partial sums

__device__ __forceinline__ float wred(float v) {
#pragma unroll
  for (int off = 32; off > 0; off >>= 1) v += __shfl_down(v, off);
  return v;
}

__global__ __launch_bounds__(256) void k_term1(
    const float* __restrict__ pm, const float* __restrict__ gt,
    const float* __restrict__ osz, float* __restrict__ ws) {
  int b = blockIdx.y;
  __shared__ float2 gts[MPTS];
  __shared__ float r1[4], r2[4];
  float nyn = osz[2*b+0] * (1.0f/HH);
  float nxn = osz[2*b+1] * (1.0f/WW);
  for (int i = threadIdx.x; i < MPTS; i += 256)
    gts[i] = make_float2(gt[(b*MPTS+i)*2+0]*nyn, gt[(b*MPTS+i)*2+1]*nxn);
  __syncthreads();
  const float2* pm2 = (const float2*)(pm + (size_t)b*NPIX);
  float t1p = 0.0f, np = 0.0f;
#pragma unroll
  for (int t = 0; t < 2; ++t) {
    int q = blockIdx.x*512 + t*256 + (int)threadIdx.x;  // float2 index
    float2 p2 = pm2[q];
    int n0 = q << 1;
    float py  = (float)(n0 >> 9) * nyn;
    float px0 = (float)(n0 & 511) * nxn;
    float px1 = px0 + nxn;
    float mA = 1e30f, mB = 1e30f;
#pragma unroll 5
    for (int m = 0; m < MPTS; m += 2) {
      float2 ga = gts[m];
      float2 gb = gts[m+1];
      float dya = py - ga.x; float ya2 = dya*dya;
      float dyb = py - gb.x; float yb2 = dyb*dyb;
      float a0 = px0 - ga.y, b0 = px0 - gb.y;
      float a1 = px1 - ga.y, b1 = px1 - gb.y;
      // fminf(chain, fminf(x,y)) -> v_min3_f32
      mA = fminf(mA, fminf(fmaf(a0,a0,ya2), fmaf(b0,b0,yb2)));
      mB = fminf(mB, fminf(fmaf(a1,a1,ya2), fmaf(b1,b1,yb2)));
    }
    t1p += p2.x*__builtin_amdgcn_sqrtf(mA) + p2.y*__builtin_amdgcn_sqrtf(mB);
    np  += p2.x + p2.y;
  }
  t1p = wred(t1p);
  np  = wred(np);
  int w = threadIdx.x >> 6;
  if ((threadIdx.x & 63) == 0) { r1[w] = t1p; r2[w] = np; }
  __syncthreads();
  if (threadIdx.x == 0) {
    ws[b*T1B + blockIdx.x]        = (r1[0]+r1[1])+(r1[2]+r1[3]);
    ws[1024 + b*T1B + blockIdx.x] = (r2[0]+r2[1])+(r2[2]+r2[3]);
  }
}

__global__ __launch_bounds__(256) void k_term2(
    const float* __restrict__ pm, const float* __restrict__ gt,
    const float* __restrict__ osz, float* __restrict__ S2) {
  const int PB = 4;    // float4 groups per thread
  int b  = blockIdx.z;
  int mg = blockIdx.y;
  __shared__ float sacc[4][TM];
  float nyn = osz[2*b+0] * (1.0f/HH);
  float nxn = osz[2*b+1] * (1.0f/WW);
  float gy[TM], gx[TM];
#pragma unroll
  for (int j = 0; j < TM; ++j) {
    int m = mg*TM + j;
    gy[j] = gt[(b*MPTS+m)*2+0]*nyn;
    gx[j] = gt[(b*MPTS+m)*2+1]*nxn;
  }
  float acc[TM];
#pragma unroll
  for (int j = 0; j < TM; ++j) acc[j] = 0.0f;
  const float4* pm4 = (const float4*)(pm + (size_t)b*NPIX);
  int base = blockIdx.x * (256*PB);
#pragma unroll
  for (int t = 0; t < PB; ++t) {
    int q = base + t*256 + (int)threadIdx.x;
    float4 p4 = pm4[q];
    int n0 = q << 2;
    float py  = (float)(n0 >> 9) * nyn;
    float px0 = (float)(n0 & 511) * nxn;
    // c = (1-p)*MAXD + EPS
    float c0 = fmaf(-p4.x, MAXD, MAXD + EPSF);
    float c1 = fmaf(-p4.y, MAXD, MAXD + EPSF);
    float c2 = fmaf(-p4.z, MAXD, MAXD + EPSF);
    float c3 = fmaf(-p4.w, MAXD, MAXD + EPSF);
#pragma unroll
    for (int j = 0; j < TM; ++j) {
      float dy  = py - gy[j];
      float dy2 = dy*dy;
      float dx0 = px0 - gx[j];
      float dx1 = dx0 + nxn;
      float dx2 = dx1 + nxn;
      float dx3 = dx2 + nxn;
      float w0 = fmaf(p4.x, __builtin_amdgcn_sqrtf(fmaf(dx0,dx0,dy2)), c0);
      float w1 = fmaf(p4.y, __builtin_amdgcn_sqrtf(fmaf(dx1,dx1,dy2)), c1);
      float w2 = fmaf(p4.z, __builtin_amdgcn_sqrtf(fmaf(dx2,dx2,dy2)), c2);
      float w3 = fmaf(p4.w, __builtin_amdgcn_sqrtf(fmaf(dx3,dx3,dy2)), c3);
      float i0 = __builtin_amdgcn_rcpf(w0);
      float i1 = __builtin_amdgcn_rcpf(w1);
      float i2 = __builtin_amdgcn_rcpf(w2);
      float i3 = __builtin_amdgcn_rcpf(w3);
      float a0 = i0*i0; a0 *= a0; a0 *= a0;   // i^8
      float a1 = i1*i1; a1 *= a1; a1 *= a1;
      float a2 = i2*i2; a2 *= a2; a2 *= a2;
      float a3 = i3*i3; a3 *= a3; a3 *= a3;
      float s = fmaf(a0, i0, acc[j]);
      s = fmaf(a1, i1, s);
      s = fmaf(a2, i2, s);
      acc[j] = fmaf(a3, i3, s);
    }
  }
  int w = threadIdx.x >> 6;
#pragma unroll
  for (int j = 0; j < TM; ++j) {
    float v = wred(acc[j]);
    if ((threadIdx.x & 63) == 0) sacc[w][j] = v;
  }
  __syncthreads();
  if (threadIdx.x < TM) {
    float s = (sacc[0][threadIdx.x] + sacc[1][threadIdx.x])
            + (sacc[2][threadIdx.x] + sacc[3][threadIdx.x]);
    S2[(b*MPTS + mg*TM + (int)threadIdx.x)*NCH + blockIdx.x] = s;
  }
}

__global__ __launch_bounds__(512) void k_final(
    const float* __restrict__ ws, float* __restrict__ out) {
  __shared__ float smT[512], smA[512], smN[512];
  int i = threadIdx.x;
  // term2: reduce chunks, power mean
  float v = 0.0f;
  if (i < BSZ*MPTS) {
    const float* p = ws + 2048 + i*NCH;
    float s = 0.0f;
#pragma unroll
    for (int c = 0; c < NCH; ++c) s += p[c];
    // (s/N)^(-1/9) = exp2(log2(s/N) * -1/9)
    v = __builtin_amdgcn_exp2f(__builtin_amdgcn_logf(s * (1.0f/(float)NPIX))
                               * (-1.0f/9.0f));
  }
  smT[i] = v;
  __syncthreads();
  for (int s = 256; s > 0; s >>= 1) {
    if (i < s) smT[i] += smT[i+s];
    __syncthreads();
  }
  // term1: per-batch reduce of T1B=256 partials (2 per thread, then tree over 128)
  int b = i >> 7, j = i & 127;
  smA[i] = ws[b*T1B + j]        + ws[b*T1B + j + 128];
  smN[i] = ws[1024 + b*T1B + j] + ws[1024 + b*T1B + j + 128];
  __syncthreads();
  for (int s = 64; s > 0; s >>= 1) {
    if (j < s) { smA[i] += smA[i+s]; smN[i] += smN[i+s]; }
    __syncthreads();
  }
  if (i == 0) {
    float t1 = 0.0f;
    for (int bb = 0; bb < BSZ; ++bb)
      t1 += smA[bb*128] / (smN[bb*128] + EPSF);
    out[0] = t1 * (1.0f/(float)BSZ) + smT[0] * (1.0f/(float)(BSZ*MPTS));
  }
}

extern "C" void kernel_launch(void* const* d_in, const int* in_sizes, int n_in,
                              void* d_out, int out_size, void* d_ws, size_t ws_size,
                              hipStream_t stream) {
  const float* pm  = (const float*)d_in[0];
  const float* gt  = (const float*)d_in[1];
  const float* osz = (const float*)d_in[2];
  float* out = (float*)d_out;
  float* ws  = (float*)d_ws;

  // term1: 256 blocks/batch x 4 batches = 1024 blocks, 4 px/thread, no atomics
  k_term1<<<dim3(T1B, BSZ), 256, 0, stream>>>(pm, gt, osz, ws);

  // term2: 64 chunks x 10 m-groups x 4 batches = 2560 blocks, no atomics
  k_term2<<<dim3(NCH, MPTS/TM, BSZ), 256, 0, stream>>>(pm, gt, osz, ws + 2048);

  // single-block hierarchical reduce + power-mean + final scalar
  k_final<<<1, 512, 0, stream>>>(ws, out);
}